// Round 14
// baseline (179.970 us; speedup 1.0000x reference)
//
#include <hip/hip_runtime.h>

#define N_FEAT 128
#define HID 256
#define OUT_CH 128

#define NB 256        // CSR-build blocks (per-block histograms)
#define MAXN 10240    // LDS histogram capacity (N=10000)
#define CH 16         // column-scan chunks
#define CB (NB / CH)  // blocks per chunk (16)

typedef float f32x2 __attribute__((ext_vector_type(2)));

// ---------------- bf16 pack/unpack helpers ----------------
__device__ __forceinline__ unsigned bf16rn(float f) {
    unsigned u = __float_as_uint(f);
    return (u + 0x7fffu + ((u >> 16) & 1u)) >> 16;
}
__device__ __forceinline__ unsigned pack_bf16x2(float lo, float hi) {
    return bf16rn(lo) | (bf16rn(hi) << 16);
}
__device__ __forceinline__ float2 unpack_bf16x2(unsigned u) {
    float2 r;
    r.x = __uint_as_float(u << 16);
    r.y = __uint_as_float(u & 0xffff0000u);
    return r;
}
__device__ __forceinline__ f32x2 unpack_bf16x2v(unsigned u) {
    f32x2 r;
    r.x = __uint_as_float(u << 16);
    r.y = __uint_as_float(u & 0xffff0000u);
    return r;
}

// ---------------- CSR build: LDS-histogram counting sort ----------------

__global__ __launch_bounds__(256)
void hist_kernel(const int* __restrict__ dst, unsigned short* __restrict__ bh,
                 int E, int N, int chunk) {
    __shared__ int hist[MAXN];
    for (int i = threadIdx.x; i < N; i += 256) hist[i] = 0;
    __syncthreads();
    int base = blockIdx.x * chunk;
    int lim = min(chunk, E - base);
    for (int i = threadIdx.x; i < lim; i += 256) {
        int d = dst[base + i];
        if (d >= 0 && d < N) atomicAdd(&hist[d], 1);
    }
    __syncthreads();
    unsigned short* out = bh + (size_t)blockIdx.x * N;
    for (int i = threadIdx.x; i < N; i += 256) out[i] = (unsigned short)hist[i];
}

// Fused: per-chunk partial sums + exclusive chunk scan + deg + dinv. (grid: NJ)
__global__ __launch_bounds__(256)
void colscan_kernel(const unsigned short* __restrict__ bh,
                    int* __restrict__ ps, int* __restrict__ counts,
                    float* __restrict__ dinv, int N) {
    int j = blockIdx.x * 256 + threadIdx.x;
    if (j >= N) return;
    int run = 0;
    for (int c = 0; c < CH; c++) {
        int s = 0;
        #pragma unroll
        for (int b = c * CB; b < (c + 1) * CB; b++) s += bh[(size_t)b * N + j];
        ps[(size_t)c * N + j] = run;   // exclusive chunk prefix
        run += s;
    }
    counts[j] = run;
    dinv[j] = rsqrtf((float)(run + 1));
}

// Single-block hybrid scan: row_start = exclusive-scan(counts).
#define SCAN_T 1024
#define SCAN_MAX_PER 16
__global__ __launch_bounds__(SCAN_T)
void scan_kernel(const int* __restrict__ counts,
                 int* __restrict__ row_start, int n) {
    int tid = threadIdx.x;
    int per = (n + SCAN_T - 1) / SCAN_T;
    int base = tid * per;
    int local[SCAN_MAX_PER];
    int sum = 0;
    for (int j = 0; j < per; j++) {
        int i = base + j;
        int c = (i < n) ? counts[i] : 0;
        local[j] = sum;
        sum += c;
    }
    int lane = tid & 63;
    int wave = tid >> 6;
    int incl = sum;
    #pragma unroll
    for (int off = 1; off < 64; off <<= 1) {
        int t = __shfl_up(incl, off, 64);
        if (lane >= off) incl += t;
    }
    __shared__ int wsum[16];
    __shared__ int woff[16];
    if (lane == 63) wsum[wave] = incl;
    __syncthreads();
    if (wave == 0) {
        int w = (lane < 16) ? wsum[lane] : 0;
        int v = w;
        #pragma unroll
        for (int off = 1; off < 16; off <<= 1) {
            int t = __shfl_up(v, off, 64);
            if (lane >= off) v += t;
        }
        if (lane < 16) woff[lane] = v - w;
    }
    __syncthreads();
    int thread_excl = woff[wave] + (incl - sum);
    for (int j = 0; j < per; j++) {
        int i = base + j;
        if (i < n) row_start[i] = thread_excl + local[j];
    }
    if (tid == SCAN_T - 1) row_start[n] = thread_excl + sum;
}

// Within-chunk replay: bh[b][j] <- per-column exclusive prefix (u16).
__global__ __launch_bounds__(256)
void chunkbase_kernel(unsigned short* __restrict__ bh,
                      const int* __restrict__ ps, int N) {
    int j = blockIdx.x * 256 + threadIdx.x;
    if (j >= N) return;
    int c = blockIdx.y;
    int run = ps[(size_t)c * N + j];
    #pragma unroll
    for (int b = c * CB; b < (c + 1) * CB; b++) {
        size_t idx = (size_t)b * N + j;
        int t = bh[idx];
        bh[idx] = (unsigned short)run;
        run += t;
    }
}

// Scatter via LDS cursors (no global atomics). csr_src stored as u16.
__global__ __launch_bounds__(256)
void scat_kernel(const int* __restrict__ src, const int* __restrict__ dst,
                 const unsigned short* __restrict__ bh,
                 const int* __restrict__ row_start,
                 unsigned short* __restrict__ csr_src, int E, int N, int chunk) {
    __shared__ int cur[MAXN];
    const unsigned short* basep = bh + (size_t)blockIdx.x * N;
    for (int i = threadIdx.x; i < N; i += 256)
        cur[i] = row_start[i] + (int)basep[i];
    __syncthreads();
    int base = blockIdx.x * chunk;
    int lim = min(chunk, E - base);
    for (int i = threadIdx.x; i < lim; i += 256) {
        int e = base + i;
        int d = dst[e];
        if (d < 0 || d >= N) continue;
        int pos = atomicAdd(&cur[d], 1);
        if ((unsigned)pos < (unsigned)E) csr_src[pos] = (unsigned short)src[e];
    }
}

// ---------------- prescale + fp32->bf16: xs[n,:] = bf16(dinv[n] * x[n,:]) ----------------
__global__ void prescale_kernel(const float* __restrict__ x,
                                const float* __restrict__ dinv,
                                unsigned* __restrict__ xs_b, int total4) {
    int i = blockIdx.x * blockDim.x + threadIdx.x;
    if (i < total4) {
        int row = i >> 5;                // 32 float4 per 128-f row
        float d = dinv[row];
        float4 v = ((const float4*)x)[i];
        uint2 p;
        p.x = pack_bf16x2(v.x * d, v.y * d);
        p.y = pack_bf16x2(v.z * d, v.w * d);
        ((uint2*)xs_b)[i] = p;
    }
}

// ---------------- Aggregation (bf16 table, fp32 accumulate) ----------------
// 32 lanes per node-row (uint2 = 4 feats/lane); wave processes 2 edges per
// gather instruction (even/odd halves), u16 index PAIRS (one unsigned = 2
// edges), pipelined batch-8. Array regs: 4+4 unsigned + 4 uint2 = 20 VGPRs
// (r7's spilling variant needed ~96 -- safe). Cross-half shfl_xor reduce.
template <bool EPILOGUE>
__global__ __launch_bounds__(256)
void agg_kernel(const unsigned* __restrict__ featb,
                const float* __restrict__ dinv,
                const int* __restrict__ row_start,
                const unsigned short* __restrict__ csr_src,
                const float* __restrict__ bias,
                float* __restrict__ out, int N) {
    int wave = threadIdx.x >> 6;
    int n = blockIdx.x * 4 + wave;
    if (n >= N) return;
    int l = threadIdx.x & 63;
    int half = l >> 5;        // 0: even edges, 1: odd edges
    int fl = l & 31;          // feature quad (feats 4*fl .. 4*fl+3)
    const uint2* feat2 = (const uint2*)featb;   // row stride 32 uint2 = 256B
    f32x2 a01 = {0.f, 0.f}, a23 = {0.f, 0.f};
    if (half == 0) {          // self-loop term counted once
        uint2 s = feat2[(size_t)n * 32 + fl];
        a01 = unpack_bf16x2v(s.x);
        a23 = unpack_bf16x2v(s.y);
    }
    int e0 = row_start[n], e1 = row_start[n + 1];
    int e = e0;
    if ((e & 1) && e < e1) {  // align e to even for pair loads
        if (half == 0) {
            uint2 w = feat2[(size_t)csr_src[e] * 32 + fl];
            a01 += unpack_bf16x2v(w.x);
            a23 += unpack_bf16x2v(w.y);
        }
        e++;
    }
    const unsigned* cs2 = (const unsigned*)csr_src;   // 2 x u16 per load
    if (e + 8 <= e1) {
        unsigned p_cur[4];
        #pragma unroll
        for (int j = 0; j < 4; j++) p_cur[j] = cs2[(e >> 1) + j];
        e += 8;
        for (; e + 8 <= e1; e += 8) {
            // gathers for current batch (each half: 4 of the 8 edges)
            uint2 w[4];
            #pragma unroll
            for (int j = 0; j < 4; j++) {
                int s = half ? (int)(p_cur[j] >> 16) : (int)(p_cur[j] & 0xffffu);
                w[j] = feat2[(size_t)s * 32 + fl];
            }
            // next batch's index pairs (independent; overlaps gather latency)
            unsigned p_nxt[4];
            #pragma unroll
            for (int j = 0; j < 4; j++) p_nxt[j] = cs2[(e >> 1) + j];
            // consume (packed adds)
            #pragma unroll
            for (int j = 0; j < 4; j++) {
                a01 += unpack_bf16x2v(w[j].x);
                a23 += unpack_bf16x2v(w[j].y);
            }
            #pragma unroll
            for (int j = 0; j < 4; j++) p_cur[j] = p_nxt[j];
        }
        // drain final full batch
        uint2 w[4];
        #pragma unroll
        for (int j = 0; j < 4; j++) {
            int s = half ? (int)(p_cur[j] >> 16) : (int)(p_cur[j] & 0xffffu);
            w[j] = feat2[(size_t)s * 32 + fl];
        }
        #pragma unroll
        for (int j = 0; j < 4; j++) {
            a01 += unpack_bf16x2v(w[j].x);
            a23 += unpack_bf16x2v(w[j].y);
        }
    }
    for (; e + 2 <= e1; e += 2) {
        unsigned p = cs2[e >> 1];
        int s = half ? (int)(p >> 16) : (int)(p & 0xffffu);
        uint2 w = feat2[(size_t)s * 32 + fl];
        a01 += unpack_bf16x2v(w.x);
        a23 += unpack_bf16x2v(w.y);
    }
    if (e < e1 && half == 0) {
        uint2 w = feat2[(size_t)csr_src[e] * 32 + fl];
        a01 += unpack_bf16x2v(w.x);
        a23 += unpack_bf16x2v(w.y);
    }
    // cross-half reduction (both halves end with the full sum)
    a01.x += __shfl_xor(a01.x, 32, 64);
    a01.y += __shfl_xor(a01.y, 32, 64);
    a23.x += __shfl_xor(a23.x, 32, 64);
    a23.y += __shfl_xor(a23.y, 32, 64);
    float dn = dinv[n];
    a01 *= dn;
    a23 *= dn;
    if (EPILOGUE) {
        float4 b = ((const float4*)bias)[fl];
        a01.x = fmaxf(a01.x + b.x, 0.0f);
        a01.y = fmaxf(a01.y + b.y, 0.0f);
        a23.x = fmaxf(a23.x + b.z, 0.0f);
        a23.y = fmaxf(a23.y + b.w, 0.0f);
    }
    if (half == 0) {
        float4 r;
        r.x = a01.x; r.y = a01.y; r.z = a23.x; r.w = a23.y;
        ((float4*)out)[(size_t)n * 32 + fl] = r;
    }
}

// ---------------- fp32 tiled GEMM: C[M,N] = A[M,K] @ B[K,N] ----------------
// Round-8 proven: 64x64 tile, 256 threads, 4x4 microtile, BK=16;
// float4 staging + b128 LDS reads.
template <bool BIAS_RELU, bool RSCALE, bool BF16_OUT>
__global__ __launch_bounds__(256)
void gemm_kernel(const float* __restrict__ A,
                 const float* __restrict__ B,
                 const float* __restrict__ bias,
                 const float* __restrict__ rscale,
                 void* __restrict__ Cv, int M, int N, int K) {
    __shared__ float As[16][68];   // stride 272B: 16B-aligned, 2-way banks (free)
    __shared__ float Bs[16][64];
    int tid = threadIdx.x;
    int n0 = blockIdx.x * 64;
    int m0 = blockIdx.y * 64;
    int tx = tid & 15;
    int ty = tid >> 4;
    int ar = tid >> 2;            // A-stage row 0..63
    int akq = tid & 3;            // A-stage k-quad 0..3
    int bk = tid >> 4;            // B-stage k 0..15
    int bnq = tid & 15;           // B-stage n-quad 0..15
    float acc[4][4] = {};
    for (int k0 = 0; k0 < K; k0 += 16) {
        float4 av = make_float4(0.f, 0.f, 0.f, 0.f);
        if (m0 + ar < M)
            av = *(const float4*)&A[(size_t)(m0 + ar) * K + k0 + akq * 4];
        float4 bv = *(const float4*)&B[(size_t)(k0 + bk) * N + n0 + bnq * 4];
        As[akq * 4 + 0][ar] = av.x;
        As[akq * 4 + 1][ar] = av.y;
        As[akq * 4 + 2][ar] = av.z;
        As[akq * 4 + 3][ar] = av.w;
        *(float4*)&Bs[bk][bnq * 4] = bv;
        __syncthreads();
        #pragma unroll
        for (int k = 0; k < 16; k++) {
            float4 ra = *(const float4*)&As[k][ty * 4];
            float4 rb = *(const float4*)&Bs[k][tx * 4];
            acc[0][0] = fmaf(ra.x, rb.x, acc[0][0]);
            acc[0][1] = fmaf(ra.x, rb.y, acc[0][1]);
            acc[0][2] = fmaf(ra.x, rb.z, acc[0][2]);
            acc[0][3] = fmaf(ra.x, rb.w, acc[0][3]);
            acc[1][0] = fmaf(ra.y, rb.x, acc[1][0]);
            acc[1][1] = fmaf(ra.y, rb.y, acc[1][1]);
            acc[1][2] = fmaf(ra.y, rb.z, acc[1][2]);
            acc[1][3] = fmaf(ra.y, rb.w, acc[1][3]);
            acc[2][0] = fmaf(ra.z, rb.x, acc[2][0]);
            acc[2][1] = fmaf(ra.z, rb.y, acc[2][1]);
            acc[2][2] = fmaf(ra.z, rb.z, acc[2][2]);
            acc[2][3] = fmaf(ra.z, rb.w, acc[2][3]);
            acc[3][0] = fmaf(ra.w, rb.x, acc[3][0]);
            acc[3][1] = fmaf(ra.w, rb.y, acc[3][1]);
            acc[3][2] = fmaf(ra.w, rb.z, acc[3][2]);
            acc[3][3] = fmaf(ra.w, rb.w, acc[3][3]);
        }
        __syncthreads();
    }
    #pragma unroll
    for (int i = 0; i < 4; i++) {
        int m = m0 + ty * 4 + i;
        if (m >= M) continue;
        float rs = RSCALE ? rscale[m] : 1.0f;
        float v[4];
        #pragma unroll
        for (int j = 0; j < 4; j++) {
            v[j] = acc[i][j];
            if (RSCALE) v[j] *= rs;
            if (BIAS_RELU) v[j] = fmaxf(v[j] + bias[n0 + tx * 4 + j], 0.0f);
        }
        if (BF16_OUT) {
            unsigned* Cb = (unsigned*)Cv;
            size_t base = (size_t)m * (N >> 1) + ((n0 + tx * 4) >> 1);
            Cb[base] = pack_bf16x2(v[0], v[1]);
            Cb[base + 1] = pack_bf16x2(v[2], v[3]);
        } else {
            float* C = (float*)Cv;
            #pragma unroll
            for (int j = 0; j < 4; j++)
                C[(size_t)m * N + n0 + tx * 4 + j] = v[j];
        }
    }
}

// ---------------- launch ----------------

static inline size_t align512(size_t x) { return (x + 511) & ~(size_t)511; }

extern "C" void kernel_launch(void* const* d_in, const int* in_sizes, int n_in,
                              void* d_out, int out_size, void* d_ws, size_t ws_size,
                              hipStream_t stream) {
    const float* x = (const float*)d_in[0];
    const int* ei = (const int*)d_in[1];
    const float* W1 = (const float*)d_in[2];
    const float* b1 = (const float*)d_in[3];
    const float* W2 = (const float*)d_in[4];
    const float* b2 = (const float*)d_in[5];
    float* out = (float*)d_out;

    const int N = in_sizes[0] / N_FEAT;      // 10000
    const int E = in_sizes[1] / 2;           // 640000
    const int* src = ei;
    const int* dst = ei + E;

    // workspace carve-up (~23 MB)
    char* ws = (char*)d_ws;
    size_t off = 0;
    float* dinv = (float*)(ws + off);    off += align512((size_t)N * 4);
    int* counts = (int*)(ws + off);      off += align512((size_t)N * 4);
    int* row_start = (int*)(ws + off);   off += align512((size_t)(N + 1) * 4);
    unsigned short* csr_src = (unsigned short*)(ws + off);
    off += align512((size_t)E * 2);
    unsigned* xs_b = (unsigned*)(ws + off); off += align512((size_t)N * 64 * 4);
    float* h = (float*)(ws + off);       off += align512((size_t)N * HID * 4);
    unsigned* t_b = (unsigned*)(ws + off); off += align512((size_t)N * 64 * 4);
    int* ps = (int*)(ws + off);          off += align512((size_t)CH * N * 4);
    unsigned short* bh = (unsigned short*)(ws + off);
    off += align512((size_t)NB * N * 2);
    (void)ws_size;
    float* agg1 = out;   // layer-1 aggregate borrows d_out (consumed by gemm1)
    const int chunk = (E + NB - 1) / NB;
    const int NJ = (N + 255) / 256;

    // 1. CSR build (no global atomics; 2-D parallel column scans)
    hist_kernel<<<NB, 256, 0, stream>>>(dst, bh, E, N, chunk);
    colscan_kernel<<<NJ, 256, 0, stream>>>(bh, ps, counts, dinv, N);
    scan_kernel<<<1, SCAN_T, 0, stream>>>(counts, row_start, N);
    chunkbase_kernel<<<dim3(NJ, CH), 256, 0, stream>>>(bh, ps, N);
    scat_kernel<<<NB, 256, 0, stream>>>(src, dst, bh, row_start, csr_src, E, N, chunk);

    // 2. xs_b = bf16(dinv[row] * x)
    {
        int total4 = N * N_FEAT / 4;
        prescale_kernel<<<(total4 + 255) / 256, 256, 0, stream>>>(x, dinv, xs_b, total4);
    }

    // 3. agg1 = A_norm @ x   (fp32 out)
    agg_kernel<false><<<(N + 3) / 4, 256, 0, stream>>>(xs_b, dinv, row_start, csr_src,
                                                       nullptr, agg1, N);

    // 4. h = relu(agg1 @ W1 + b1)
    {
        dim3 grid(HID / 64, (N + 63) / 64);
        gemm_kernel<true, false, false><<<grid, 256, 0, stream>>>(
            agg1, W1, b1, nullptr, h, N, HID, N_FEAT);
    }

    // 5. t_b = bf16(dinv[m] * (h @ W2))
    {
        dim3 grid(OUT_CH / 64, (N + 63) / 64);
        gemm_kernel<false, true, true><<<grid, 256, 0, stream>>>(
            h, W2, nullptr, dinv, t_b, N, OUT_CH, HID);
    }

    // 6. out = relu(A_norm-aggregate of t + b2)
    agg_kernel<true><<<(N + 3) / 4, 256, 0, stream>>>(t_b, dinv, row_start, csr_src,
                                                      b2, out, N);
}

// Round 15
// 175.336 us; speedup vs baseline: 1.0264x; 1.0264x over previous
//
#include <hip/hip_runtime.h>

#define N_FEAT 128
#define HID 256
#define OUT_CH 128

#define NB 256        // CSR-build blocks (per-block histograms)
#define MAXN 10240    // LDS histogram capacity (N=10000)
#define CH 16         // column-scan chunks
#define CB (NB / CH)  // blocks per chunk (16)

// ---------------- bf16 pack/unpack helpers ----------------
__device__ __forceinline__ unsigned bf16rn(float f) {
    unsigned u = __float_as_uint(f);
    return (u + 0x7fffu + ((u >> 16) & 1u)) >> 16;
}
__device__ __forceinline__ unsigned pack_bf16x2(float lo, float hi) {
    return bf16rn(lo) | (bf16rn(hi) << 16);
}
__device__ __forceinline__ float2 unpack_bf16x2(unsigned u) {
    float2 r;
    r.x = __uint_as_float(u << 16);
    r.y = __uint_as_float(u & 0xffff0000u);
    return r;
}

// ---------------- CSR build: LDS-histogram counting sort ----------------

__global__ __launch_bounds__(256)
void hist_kernel(const int* __restrict__ dst, unsigned short* __restrict__ bh,
                 int E, int N, int chunk) {
    __shared__ int hist[MAXN];
    for (int i = threadIdx.x; i < N; i += 256) hist[i] = 0;
    __syncthreads();
    int base = blockIdx.x * chunk;
    int lim = min(chunk, E - base);
    for (int i = threadIdx.x; i < lim; i += 256) {
        int d = dst[base + i];
        if (d >= 0 && d < N) atomicAdd(&hist[d], 1);
    }
    __syncthreads();
    unsigned short* out = bh + (size_t)blockIdx.x * N;
    for (int i = threadIdx.x; i < N; i += 256) out[i] = (unsigned short)hist[i];
}

// Fused: per-chunk partial sums + exclusive chunk scan + deg + dinv. (grid: NJ)
__global__ __launch_bounds__(256)
void colscan_kernel(const unsigned short* __restrict__ bh,
                    int* __restrict__ ps, int* __restrict__ counts,
                    float* __restrict__ dinv, int N) {
    int j = blockIdx.x * 256 + threadIdx.x;
    if (j >= N) return;
    int run = 0;
    for (int c = 0; c < CH; c++) {
        int s = 0;
        #pragma unroll
        for (int b = c * CB; b < (c + 1) * CB; b++) s += bh[(size_t)b * N + j];
        ps[(size_t)c * N + j] = run;   // exclusive chunk prefix
        run += s;
    }
    counts[j] = run;
    dinv[j] = rsqrtf((float)(run + 1));
}

// Single-block hybrid scan: row_start = exclusive-scan(counts).
#define SCAN_T 1024
#define SCAN_MAX_PER 16
__global__ __launch_bounds__(SCAN_T)
void scan_kernel(const int* __restrict__ counts,
                 int* __restrict__ row_start, int n) {
    int tid = threadIdx.x;
    int per = (n + SCAN_T - 1) / SCAN_T;
    int base = tid * per;
    int local[SCAN_MAX_PER];
    int sum = 0;
    for (int j = 0; j < per; j++) {
        int i = base + j;
        int c = (i < n) ? counts[i] : 0;
        local[j] = sum;
        sum += c;
    }
    int lane = tid & 63;
    int wave = tid >> 6;
    int incl = sum;
    #pragma unroll
    for (int off = 1; off < 64; off <<= 1) {
        int t = __shfl_up(incl, off, 64);
        if (lane >= off) incl += t;
    }
    __shared__ int wsum[16];
    __shared__ int woff[16];
    if (lane == 63) wsum[wave] = incl;
    __syncthreads();
    if (wave == 0) {
        int w = (lane < 16) ? wsum[lane] : 0;
        int v = w;
        #pragma unroll
        for (int off = 1; off < 16; off <<= 1) {
            int t = __shfl_up(v, off, 64);
            if (lane >= off) v += t;
        }
        if (lane < 16) woff[lane] = v - w;
    }
    __syncthreads();
    int thread_excl = woff[wave] + (incl - sum);
    for (int j = 0; j < per; j++) {
        int i = base + j;
        if (i < n) row_start[i] = thread_excl + local[j];
    }
    if (tid == SCAN_T - 1) row_start[n] = thread_excl + sum;
}

// Within-chunk replay: bh[b][j] <- per-column exclusive prefix (u16).
__global__ __launch_bounds__(256)
void chunkbase_kernel(unsigned short* __restrict__ bh,
                      const int* __restrict__ ps, int N) {
    int j = blockIdx.x * 256 + threadIdx.x;
    if (j >= N) return;
    int c = blockIdx.y;
    int run = ps[(size_t)c * N + j];
    #pragma unroll
    for (int b = c * CB; b < (c + 1) * CB; b++) {
        size_t idx = (size_t)b * N + j;
        int t = bh[idx];
        bh[idx] = (unsigned short)run;
        run += t;
    }
}

// Scatter via LDS cursors (no global atomics).
__global__ __launch_bounds__(256)
void scat_kernel(const int* __restrict__ src, const int* __restrict__ dst,
                 const unsigned short* __restrict__ bh,
                 const int* __restrict__ row_start,
                 int* __restrict__ csr_src, int E, int N, int chunk) {
    __shared__ int cur[MAXN];
    const unsigned short* basep = bh + (size_t)blockIdx.x * N;
    for (int i = threadIdx.x; i < N; i += 256)
        cur[i] = row_start[i] + (int)basep[i];
    __syncthreads();
    int base = blockIdx.x * chunk;
    int lim = min(chunk, E - base);
    for (int i = threadIdx.x; i < lim; i += 256) {
        int e = base + i;
        int d = dst[e];
        if (d < 0 || d >= N) continue;
        int pos = atomicAdd(&cur[d], 1);
        if ((unsigned)pos < (unsigned)E) csr_src[pos] = src[e];
    }
}

// ---------------- prescale + fp32->bf16: xs[n,:] = bf16(dinv[n] * x[n,:]) ----------------
__global__ void prescale_kernel(const float* __restrict__ x,
                                const float* __restrict__ dinv,
                                unsigned* __restrict__ xs_b, int total4) {
    int i = blockIdx.x * blockDim.x + threadIdx.x;
    if (i < total4) {
        int row = i >> 5;                // 32 float4 per 128-f row
        float d = dinv[row];
        float4 v = ((const float4*)x)[i];
        uint2 p;
        p.x = pack_bf16x2(v.x * d, v.y * d);
        p.y = pack_bf16x2(v.z * d, v.w * d);
        ((uint2*)xs_b)[i] = p;
    }
}

// ---------------- Aggregation (bf16 table, fp32 accumulate) ----------------
// Best-measured shape (round 12, 176.3 us): 2500 blocks, 4 waves/block, one
// node/wave, 64 lanes x bf16x2, software-pipelined batch-8 edge loop.
// Rejected by measurement: batch-32 (spill, r7), persistent 4-node waves
// (r9), fused MLP (r11, occupancy), u16+packed (r13, neutral), 32-lane
// pair-gather (r14, -4 us) -- agg is gather-request/latency-bound.
template <bool EPILOGUE>
__global__ __launch_bounds__(256)
void agg_kernel(const unsigned* __restrict__ featb,
                const float* __restrict__ dinv,
                const int* __restrict__ row_start,
                const int* __restrict__ csr_src,
                const float* __restrict__ bias,
                float* __restrict__ out, int N) {
    int wave = threadIdx.x >> 6;
    int n = blockIdx.x * 4 + wave;
    if (n >= N) return;
    int f = threadIdx.x & 63;
    float dn = dinv[n];
    float2 v = unpack_bf16x2(featb[(size_t)n * 64 + f]);
    float accx = v.x;
    float accy = v.y;
    int e0 = row_start[n];
    int e1 = row_start[n + 1];
    int e = e0;
    if (e + 8 <= e1) {
        int s_cur[8];
        #pragma unroll
        for (int j = 0; j < 8; j++) s_cur[j] = csr_src[e + j];
        e += 8;
        for (; e + 8 <= e1; e += 8) {
            // issue gathers for current batch (indices already resident)
            unsigned w[8];
            #pragma unroll
            for (int j = 0; j < 8; j++) w[j] = featb[(size_t)s_cur[j] * 64 + f];
            // issue next batch's index loads (independent; overlap gather latency)
            int s_nxt[8];
            #pragma unroll
            for (int j = 0; j < 8; j++) s_nxt[j] = csr_src[e + j];
            // consume current gathers
            #pragma unroll
            for (int j = 0; j < 8; j++) {
                float2 u = unpack_bf16x2(w[j]);
                accx += u.x;
                accy += u.y;
            }
            #pragma unroll
            for (int j = 0; j < 8; j++) s_cur[j] = s_nxt[j];
        }
        // drain final full batch
        unsigned w[8];
        #pragma unroll
        for (int j = 0; j < 8; j++) w[j] = featb[(size_t)s_cur[j] * 64 + f];
        #pragma unroll
        for (int j = 0; j < 8; j++) {
            float2 u = unpack_bf16x2(w[j]);
            accx += u.x;
            accy += u.y;
        }
    }
    for (; e + 4 <= e1; e += 4) {
        int s0 = csr_src[e], s1 = csr_src[e + 1];
        int s2 = csr_src[e + 2], s3 = csr_src[e + 3];
        unsigned w0 = featb[(size_t)s0 * 64 + f];
        unsigned w1 = featb[(size_t)s1 * 64 + f];
        unsigned w2 = featb[(size_t)s2 * 64 + f];
        unsigned w3 = featb[(size_t)s3 * 64 + f];
        float2 u0 = unpack_bf16x2(w0), u1 = unpack_bf16x2(w1);
        float2 u2 = unpack_bf16x2(w2), u3 = unpack_bf16x2(w3);
        accx += u0.x + u1.x + u2.x + u3.x;
        accy += u0.y + u1.y + u2.y + u3.y;
    }
    for (; e < e1; ++e) {
        float2 u = unpack_bf16x2(featb[(size_t)csr_src[e] * 64 + f]);
        accx += u.x;
        accy += u.y;
    }
    accx *= dn;
    accy *= dn;
    if (EPILOGUE) {
        float2 b = ((const float2*)bias)[f];
        accx = fmaxf(accx + b.x, 0.0f);
        accy = fmaxf(accy + b.y, 0.0f);
    }
    float2 r;
    r.x = accx;
    r.y = accy;
    ((float2*)out)[(size_t)n * 64 + f] = r;
}

// ---------------- fp32 tiled GEMM: C[M,N] = A[M,K] @ B[K,N] ----------------
// Round-8 proven: 64x64 tile, 256 threads, 4x4 microtile, BK=16;
// float4 staging + b128 LDS reads.
template <bool BIAS_RELU, bool RSCALE, bool BF16_OUT>
__global__ __launch_bounds__(256)
void gemm_kernel(const float* __restrict__ A,
                 const float* __restrict__ B,
                 const float* __restrict__ bias,
                 const float* __restrict__ rscale,
                 void* __restrict__ Cv, int M, int N, int K) {
    __shared__ float As[16][68];   // stride 272B: 16B-aligned, 2-way banks (free)
    __shared__ float Bs[16][64];
    int tid = threadIdx.x;
    int n0 = blockIdx.x * 64;
    int m0 = blockIdx.y * 64;
    int tx = tid & 15;
    int ty = tid >> 4;
    int ar = tid >> 2;            // A-stage row 0..63
    int akq = tid & 3;            // A-stage k-quad 0..3
    int bk = tid >> 4;            // B-stage k 0..15
    int bnq = tid & 15;           // B-stage n-quad 0..15
    float acc[4][4] = {};
    for (int k0 = 0; k0 < K; k0 += 16) {
        float4 av = make_float4(0.f, 0.f, 0.f, 0.f);
        if (m0 + ar < M)
            av = *(const float4*)&A[(size_t)(m0 + ar) * K + k0 + akq * 4];
        float4 bv = *(const float4*)&B[(size_t)(k0 + bk) * N + n0 + bnq * 4];
        As[akq * 4 + 0][ar] = av.x;
        As[akq * 4 + 1][ar] = av.y;
        As[akq * 4 + 2][ar] = av.z;
        As[akq * 4 + 3][ar] = av.w;
        *(float4*)&Bs[bk][bnq * 4] = bv;
        __syncthreads();
        #pragma unroll
        for (int k = 0; k < 16; k++) {
            float4 ra = *(const float4*)&As[k][ty * 4];
            float4 rb = *(const float4*)&Bs[k][tx * 4];
            acc[0][0] = fmaf(ra.x, rb.x, acc[0][0]);
            acc[0][1] = fmaf(ra.x, rb.y, acc[0][1]);
            acc[0][2] = fmaf(ra.x, rb.z, acc[0][2]);
            acc[0][3] = fmaf(ra.x, rb.w, acc[0][3]);
            acc[1][0] = fmaf(ra.y, rb.x, acc[1][0]);
            acc[1][1] = fmaf(ra.y, rb.y, acc[1][1]);
            acc[1][2] = fmaf(ra.y, rb.z, acc[1][2]);
            acc[1][3] = fmaf(ra.y, rb.w, acc[1][3]);
            acc[2][0] = fmaf(ra.z, rb.x, acc[2][0]);
            acc[2][1] = fmaf(ra.z, rb.y, acc[2][1]);
            acc[2][2] = fmaf(ra.z, rb.z, acc[2][2]);
            acc[2][3] = fmaf(ra.z, rb.w, acc[2][3]);
            acc[3][0] = fmaf(ra.w, rb.x, acc[3][0]);
            acc[3][1] = fmaf(ra.w, rb.y, acc[3][1]);
            acc[3][2] = fmaf(ra.w, rb.z, acc[3][2]);
            acc[3][3] = fmaf(ra.w, rb.w, acc[3][3]);
        }
        __syncthreads();
    }
    #pragma unroll
    for (int i = 0; i < 4; i++) {
        int m = m0 + ty * 4 + i;
        if (m >= M) continue;
        float rs = RSCALE ? rscale[m] : 1.0f;
        float v[4];
        #pragma unroll
        for (int j = 0; j < 4; j++) {
            v[j] = acc[i][j];
            if (RSCALE) v[j] *= rs;
            if (BIAS_RELU) v[j] = fmaxf(v[j] + bias[n0 + tx * 4 + j], 0.0f);
        }
        if (BF16_OUT) {
            unsigned* Cb = (unsigned*)Cv;
            size_t base = (size_t)m * (N >> 1) + ((n0 + tx * 4) >> 1);
            Cb[base] = pack_bf16x2(v[0], v[1]);
            Cb[base + 1] = pack_bf16x2(v[2], v[3]);
        } else {
            float* C = (float*)Cv;
            #pragma unroll
            for (int j = 0; j < 4; j++)
                C[(size_t)m * N + n0 + tx * 4 + j] = v[j];
        }
    }
}

// ---------------- launch ----------------

static inline size_t align512(size_t x) { return (x + 511) & ~(size_t)511; }

extern "C" void kernel_launch(void* const* d_in, const int* in_sizes, int n_in,
                              void* d_out, int out_size, void* d_ws, size_t ws_size,
                              hipStream_t stream) {
    const float* x = (const float*)d_in[0];
    const int* ei = (const int*)d_in[1];
    const float* W1 = (const float*)d_in[2];
    const float* b1 = (const float*)d_in[3];
    const float* W2 = (const float*)d_in[4];
    const float* b2 = (const float*)d_in[5];
    float* out = (float*)d_out;

    const int N = in_sizes[0] / N_FEAT;      // 10000
    const int E = in_sizes[1] / 2;           // 640000
    const int* src = ei;
    const int* dst = ei + E;

    // workspace carve-up (~25 MB)
    char* ws = (char*)d_ws;
    size_t off = 0;
    float* dinv = (float*)(ws + off);    off += align512((size_t)N * 4);
    int* counts = (int*)(ws + off);      off += align512((size_t)N * 4);
    int* row_start = (int*)(ws + off);   off += align512((size_t)(N + 1) * 4);
    int* csr_src = (int*)(ws + off);     off += align512((size_t)E * 4);
    unsigned* xs_b = (unsigned*)(ws + off); off += align512((size_t)N * 64 * 4);
    float* h = (float*)(ws + off);       off += align512((size_t)N * HID * 4);
    unsigned* t_b = (unsigned*)(ws + off); off += align512((size_t)N * 64 * 4);
    int* ps = (int*)(ws + off);          off += align512((size_t)CH * N * 4);
    unsigned short* bh = (unsigned short*)(ws + off);
    off += align512((size_t)NB * N * 2);
    (void)ws_size;
    float* agg1 = out;   // layer-1 aggregate borrows d_out (consumed by gemm1)
    const int chunk = (E + NB - 1) / NB;
    const int NJ = (N + 255) / 256;

    // 1. CSR build (no global atomics; 2-D parallel column scans)
    hist_kernel<<<NB, 256, 0, stream>>>(dst, bh, E, N, chunk);
    colscan_kernel<<<NJ, 256, 0, stream>>>(bh, ps, counts, dinv, N);
    scan_kernel<<<1, SCAN_T, 0, stream>>>(counts, row_start, N);
    chunkbase_kernel<<<dim3(NJ, CH), 256, 0, stream>>>(bh, ps, N);
    scat_kernel<<<NB, 256, 0, stream>>>(src, dst, bh, row_start, csr_src, E, N, chunk);

    // 2. xs_b = bf16(dinv[row] * x)
    {
        int total4 = N * N_FEAT / 4;
        prescale_kernel<<<(total4 + 255) / 256, 256, 0, stream>>>(x, dinv, xs_b, total4);
    }

    // 3. agg1 = A_norm @ x   (fp32 out)
    agg_kernel<false><<<(N + 3) / 4, 256, 0, stream>>>(xs_b, dinv, row_start, csr_src,
                                                       nullptr, agg1, N);

    // 4. h = relu(agg1 @ W1 + b1)
    {
        dim3 grid(HID / 64, (N + 63) / 64);
        gemm_kernel<true, false, false><<<grid, 256, 0, stream>>>(
            agg1, W1, b1, nullptr, h, N, HID, N_FEAT);
    }

    // 5. t_b = bf16(dinv[m] * (h @ W2))
    {
        dim3 grid(OUT_CH / 64, (N + 63) / 64);
        gemm_kernel<false, true, true><<<grid, 256, 0, stream>>>(
            h, W2, nullptr, dinv, t_b, N, OUT_CH, HID);
    }

    // 6. out = relu(A_norm-aggregate of t + b2)
    agg_kernel<true><<<(N + 3) / 4, 256, 0, stream>>>(t_b, dinv, row_start, csr_src,
                                                      b2, out, N);
}